// Round 10
// baseline (578.149 us; speedup 1.0000x reference)
//
#include <hip/hip_runtime.h>
#include <hip/hip_bf16.h>

#define N_NODES 100000
#define N_EDGES 1600000
#define N_GRAPHS 512
#define NTILES (N_NODES / 16)          // 6250, exact
#define BSH 9                          // 512 nodes per bucket
#define NBUCK ((N_NODES + 511) >> BSH) // 196
#define NB1 256                        // partition blocks
#define BST 6400                       // per-block bstore stride (max edges/block)

typedef __hip_bfloat16 bf16;
typedef unsigned int uint;
typedef unsigned short ushort;
typedef __attribute__((ext_vector_type(8))) short short8;
typedef __attribute__((ext_vector_type(4))) float float4v;
typedef __attribute__((ext_vector_type(2))) int int2v;

__device__ __forceinline__ float b2f(bf16 v) { return __bfloat162float(v); }
__device__ __forceinline__ bf16 f2b(float v) { return __float2bfloat16(v); }
__device__ __forceinline__ short f2bs(float v) { bf16 h = f2b(v); return *(short*)&h; }

__device__ __forceinline__ float ldf(const void* p, long i, int isf32) {
    return isf32 ? ((const float*)p)[i] : b2f(((const bf16*)p)[i]);
}
__device__ __forceinline__ int geti(const int* p, long i, int is64) {
    return is64 ? ((const int2v*)p)[i].x : p[i];
}
__device__ __forceinline__ float bflo(uint u) { return __uint_as_float(u << 16); }
__device__ __forceinline__ float bfhi(uint u) { return __uint_as_float(u & 0xffff0000u); }
__device__ __forceinline__ uint packbf(float x, float y) {
    bf16 a = f2b(x), b = f2b(y);
    ushort ua = *(ushort*)&a, ub = *(ushort*)&b;
    return (uint)ua | ((uint)ub << 16);
}
// fast tanh: clamp + exp ratio; |err| ~1e-6, far below bf16 rounding
__device__ __forceinline__ float tanhfast(float x) {
    float xc = fminf(fmaxf(x, -15.f), 15.f);
    float e = __expf(2.f * xc);
    return __fdividef(e - 1.f, e + 1.f);
}

// ---------------- MFMA input linear body (pre / emb) ----------------
template <int K, int KA>
__device__ __forceinline__ void mm_in_body(const void* __restrict__ A0,
                                           const void* __restrict__ W,
                                           const void* __restrict__ Bv,
                                           int isf32, bf16* __restrict__ outp,
                                           short* wT, float* bl, short (*obuf)[16 * 72],
                                           int bid, int nb) {
    const int tid = threadIdx.x;
    for (int i = tid; i < 64 * K; i += 256) {
        int k = i >> 6, f = i & 63;
        float v = (k < KA) ? ldf(W, i, isf32) : 0.f;
        wT[f * (K + 8) + k] = f2bs(v);
    }
    if (tid < 64) bl[tid] = ldf(Bv, tid, isf32);
    __syncthreads();

    const int lane = tid & 63, wv = tid >> 6;
    const int m = lane & 15, quad = lane >> 4;

    short8 bfr[4][K / 32];
    #pragma unroll
    for (int cb = 0; cb < 4; cb++)
        #pragma unroll
        for (int ks = 0; ks < K / 32; ks++)
            bfr[cb][ks] = *(const short8*)&wT[(cb * 16 + m) * (K + 8) + ks * 32 + quad * 8];

    for (int t = bid * 4 + wv; t < NTILES; t += nb * 4) {
        const int n0 = t * 16;
        short8 af[K / 32];
        if (isf32) {
            const float* Af = (const float*)A0 + (long)(n0 + m) * KA;
            #pragma unroll
            for (int ks = 0; ks < K / 32; ks++) {
                short8 a;
                #pragma unroll
                for (int j = 0; j < 8; j++) {
                    int k = ks * 32 + quad * 8 + j;
                    float v = (KA % 32 == 0 || k < KA) ? Af[k] : 0.f;
                    a[j] = f2bs(v);
                }
                af[ks] = a;
            }
        } else {
            const bf16* Ab = (const bf16*)A0 + (long)(n0 + m) * KA;
            #pragma unroll
            for (int ks = 0; ks < K / 32; ks++) {
                if constexpr (KA % 32 == 0) {
                    af[ks] = *(const short8*)&Ab[ks * 32 + quad * 8];
                } else {
                    short8 a;
                    #pragma unroll
                    for (int j = 0; j < 8; j++) {
                        int k = ks * 32 + quad * 8 + j;
                        float v = (k < KA) ? b2f(Ab[k]) : 0.f;
                        a[j] = f2bs(v);
                    }
                    af[ks] = a;
                }
            }
        }
        float4v c[4];
        #pragma unroll
        for (int cb = 0; cb < 4; cb++) { c[cb][0]=0.f; c[cb][1]=0.f; c[cb][2]=0.f; c[cb][3]=0.f; }
        #pragma unroll
        for (int ks = 0; ks < K / 32; ks++)
            #pragma unroll
            for (int cb = 0; cb < 4; cb++)
                c[cb] = __builtin_amdgcn_mfma_f32_16x16x32_bf16(af[ks], bfr[cb][ks], c[cb], 0, 0, 0);
        #pragma unroll
        for (int cb = 0; cb < 4; cb++) {
            int feat = cb * 16 + m;
            #pragma unroll
            for (int r = 0; r < 4; r++)
                obuf[wv][(quad * 4 + r) * 72 + feat] = f2bs(c[cb][r] + bl[feat]);
        }
        __builtin_amdgcn_wave_barrier();
        uint4* orow = (uint4*)(outp + (long)n0 * 64);
        #pragma unroll
        for (int it = 0; it < 2; it++) {
            int idx = it * 64 + lane;
            int row = idx >> 3, ch = idx & 7;
            orow[(long)row * 8 + ch] = *(const uint4*)&obuf[wv][row * 72 + ch * 8];
        }
        __builtin_amdgcn_wave_barrier();
    }
}

// ---------------- k_front: detect + CSR partition + pre/emb GEMM + xp/ctr zero ----------------
__global__ __launch_bounds__(256) void k_front(const int* __restrict__ ei,
                                               const void* __restrict__ x_in,
                                               const void* __restrict__ pre_w,
                                               const void* __restrict__ pre_b,
                                               const void* __restrict__ s_in,
                                               const void* __restrict__ emb_w,
                                               const void* __restrict__ emb_b,
                                               uint* __restrict__ bstore,
                                               int* __restrict__ hist,
                                               int* __restrict__ lsc,
                                               int* __restrict__ flags,
                                               bf16* __restrict__ x0,
                                               bf16* __restrict__ sA,
                                               float* __restrict__ xp) {
    __shared__ __align__(16) char smem[28672];
    __shared__ int fl[2];
    const int tid = threadIdx.x;
    if (tid == 0) { fl[0] = 0; fl[1] = 0; }
    __syncthreads();
    {
        const ushort* xu = (const ushort*)x_in;
        ushort u = xu[2 * tid];
        int e = (u >> 7) & 0xFF;
        int plaus = (u == 0 || (e >= 116 && e <= 132)) ? 1 : 0;
        int nz = (tid < 128 && ei[2 * tid + 1] != 0) ? 1 : 0;
        atomicAdd(&fl[0], plaus);
        atomicAdd(&fl[1], nz);
    }
    __syncthreads();
    const int isf32 = (fl[0] < 128) ? 1 : 0;
    const int i64 = (fl[1] < 8) ? 1 : 0;
    const int bb = blockIdx.x;

    if (bb == 896) {
        if (tid == 0) { flags[0] = isf32; flags[1] = i64; flags[8] = 0; }  // flags[8] = mmC ctr
        for (int i = tid; i < N_GRAPHS * 64; i += 256) xp[i] = 0.f;
        return;
    }
    if (bb < 256) {
        // ---- CSR partition ----
        int* lh = (int*)smem;              // 256 (NBUCK used)
        int* lpos = lh + 256;              // 256
        int* tmp = lpos + 256;             // 256
        uint* stage = (uint*)(tmp + 256);  // 6400
        int b = bb, t = tid;
        for (int i = t; i < NBUCK; i += 256) lh[i] = 0;
        __syncthreads();
        int rk[25], ck[25];
        #pragma unroll
        for (int k = 0; k < 25; k++) {
            int e = k * (NB1 * 256) + b * 256 + t;
            int r = 0, c = -1;
            if (e < N_EDGES) {
                r = geti(ei, e, i64);
                c = geti(ei, (long)N_EDGES + e, i64);
                atomicAdd(&lh[c >> BSH], 1);
            }
            rk[k] = r; ck[k] = c;
        }
        __syncthreads();
        int v = (t < NBUCK) ? lh[t] : 0;
        tmp[t] = v;
        __syncthreads();
        for (int off = 1; off < 256; off <<= 1) {
            int u = (t >= off) ? tmp[t - off] : 0;
            __syncthreads();
            tmp[t] += u;
            __syncthreads();
        }
        if (t < NBUCK) {
            int excl = tmp[t] - v;
            lsc[(long)t * 256 + b] = excl;
            hist[(long)t * 256 + b] = v;
            lpos[t] = excl;
        }
        __syncthreads();
        #pragma unroll
        for (int k = 0; k < 25; k++) {
            int c = ck[k];
            if (c >= 0) {
                int p = atomicAdd(&lpos[c >> BSH], 1);
                stage[p] = ((uint)rk[k] << BSH) | (uint)(c & 511);
            }
        }
        __syncthreads();
        int cnt_all = tmp[255];
        uint* dst = bstore + (long)b * BST;
        for (int i = t; i < cnt_all; i += 256) dst[i] = stage[i];
    } else {
        short* wT = (short*)smem;                              // 64*136 shorts
        float* bl = (float*)(smem + 64 * 136 * 2);             // 64 floats
        short (*obuf)[16 * 72] = (short (*)[16 * 72])(smem + 64 * 136 * 2 + 256);
        if (bb < 768)
            mm_in_body<128, 128>(x_in, pre_w, pre_b, isf32, x0, wT, bl, obuf, bb - 256, 512);
        else
            mm_in_body<32, 16>(s_in, emb_w, emb_b, isf32, sA, wT, bl, obuf, bb - 768, 128);
    }
}

// ---------------- k4 body: CSR finalize (bucket totals row-summed from hist) ----------------
__device__ __forceinline__ void k4_body(const uint* __restrict__ bstore,
                                        const int* __restrict__ hist,
                                        const int* __restrict__ lsc,
                                        int* __restrict__ deg,
                                        float* __restrict__ dinv,
                                        int* __restrict__ row_end,
                                        int* __restrict__ csr_src,
                                        int B, char* smem) {
    int* cnt   = (int*)smem;        // 512
    int* exc   = cnt + 512;         // 512
    int* tmp   = exc + 512;         // 256
    int* slen  = tmp + 256;         // 256
    int* sbase = slen + 256;        // 256
    int* bb_sp = sbase + 256;       // 1
    int t = threadIdx.x;
    cnt[t] = 0; cnt[t + 256] = 0;
    slen[t] = hist[(long)B * 256 + t];
    sbase[t] = t * BST + lsc[(long)B * 256 + t];
    // bucket total[t] = sum over all 256 partition blocks of hist[t][b]
    int v0 = 0;
    if (t < NBUCK) {
        const int4* hp = (const int4*)(hist + (long)t * 256);
        #pragma unroll 8
        for (int i = 0; i < 64; i++) { int4 h4 = hp[i]; v0 += h4.x + h4.y + h4.z + h4.w; }
    }
    tmp[t] = v0;
    __syncthreads();
    for (int off = 1; off < 256; off <<= 1) {
        int u = (t >= off) ? tmp[t - off] : 0;
        __syncthreads();
        tmp[t] += u;
        __syncthreads();
    }
    if (t == B) bb_sp[0] = tmp[t] - v0;
    __syncthreads();
    int wv = t >> 6, lane = t & 63;
    for (int j = wv; j < 256; j += 4) {
        int len = slen[j];
        const uint* src = bstore + sbase[j];
        for (int i = lane; i < len; i += 64) atomicAdd(&cnt[src[i] & 511], 1);
    }
    __syncthreads();
    int c0 = cnt[2 * t], c1 = cnt[2 * t + 1];
    tmp[t] = c0 + c1;
    __syncthreads();
    for (int off = 1; off < 256; off <<= 1) {
        int u = (t >= off) ? tmp[t - off] : 0;
        __syncthreads();
        tmp[t] += u;
        __syncthreads();
    }
    int ep = tmp[t] - (c0 + c1);
    exc[2 * t] = ep;
    exc[2 * t + 1] = ep + c0;
    int bb = bb_sp[0];
    int n0 = (B << BSH) + 2 * t;
    if (n0 < N_NODES) {
        deg[n0] = c0;
        dinv[n0] = rsqrtf((float)c0 + 1.0f);
        row_end[n0] = bb + ep + c0;
    }
    if (n0 + 1 < N_NODES) {
        deg[n0 + 1] = c1;
        dinv[n0 + 1] = rsqrtf((float)c1 + 1.0f);
        row_end[n0 + 1] = bb + ep + c0 + c1;
    }
    __syncthreads();
    for (int j = wv; j < 256; j += 4) {
        int len = slen[j];
        const uint* src = bstore + sbase[j];
        for (int i = lane; i < len; i += 64) {
            uint p = src[i];
            int pos = atomicAdd(&exc[p & 511], 1);
            csr_src[bb + pos] = (int)(p >> BSH);
        }
    }
}

// ---------------- mmA body: zsw row = [x,s]@W1 | s@Wg (GCN half UNSCALED;
// dinv applied per-source in gather DV=1) ----------------
__device__ __forceinline__ void mmA_body(const bf16* __restrict__ x,
                                         const bf16* __restrict__ s,
                                         const void* __restrict__ W1,
                                         const void* __restrict__ Wg,
                                         int isf32, bf16* __restrict__ zsw,
                                         int bid, int nb, char* smem) {
    short* wT1 = (short*)smem;                       // 64*136
    short* wTg = wT1 + 64 * 136;                     // 64*72
    short (*obuf)[16 * 136] = (short (*)[16 * 136])(wTg + 64 * 72);
    const int tid = threadIdx.x;
    for (int i = tid; i < 64 * 128; i += 256) {
        int k = i >> 6, f = i & 63;
        wT1[f * 136 + k] = f2bs(ldf(W1, i, isf32));
    }
    for (int i = tid; i < 64 * 64; i += 256) {
        int k = i >> 6, f = i & 63;
        wTg[f * 72 + k] = f2bs(ldf(Wg, i, isf32));
    }
    __syncthreads();

    const int lane = tid & 63, wv = tid >> 6;
    const int m = lane & 15, quad = lane >> 4;

    short8 w1f[4][4], wgf[4][2];
    #pragma unroll
    for (int cb = 0; cb < 4; cb++) {
        #pragma unroll
        for (int ks = 0; ks < 4; ks++)
            w1f[cb][ks] = *(const short8*)&wT1[(cb * 16 + m) * 136 + ks * 32 + quad * 8];
        #pragma unroll
        for (int ks = 0; ks < 2; ks++)
            wgf[cb][ks] = *(const short8*)&wTg[(cb * 16 + m) * 72 + ks * 32 + quad * 8];
    }

    for (int t = bid * 4 + wv; t < NTILES; t += nb * 4) {
        const int n0 = t * 16;
        short8 a[4];
        a[0] = *(const short8*)&x[(long)(n0 + m) * 64 + quad * 8];
        a[1] = *(const short8*)&x[(long)(n0 + m) * 64 + 32 + quad * 8];
        a[2] = *(const short8*)&s[(long)(n0 + m) * 64 + quad * 8];
        a[3] = *(const short8*)&s[(long)(n0 + m) * 64 + 32 + quad * 8];
        float4v cz[4], cd[4];
        #pragma unroll
        for (int cb = 0; cb < 4; cb++) {
            cz[cb][0]=0.f; cz[cb][1]=0.f; cz[cb][2]=0.f; cz[cb][3]=0.f;
            cd[cb][0]=0.f; cd[cb][1]=0.f; cd[cb][2]=0.f; cd[cb][3]=0.f;
        }
        #pragma unroll
        for (int ks = 0; ks < 4; ks++)
            #pragma unroll
            for (int cb = 0; cb < 4; cb++)
                cz[cb] = __builtin_amdgcn_mfma_f32_16x16x32_bf16(a[ks], w1f[cb][ks], cz[cb], 0, 0, 0);
        #pragma unroll
        for (int ks = 0; ks < 2; ks++)
            #pragma unroll
            for (int cb = 0; cb < 4; cb++)
                cd[cb] = __builtin_amdgcn_mfma_f32_16x16x32_bf16(a[2 + ks], wgf[cb][ks], cd[cb], 0, 0, 0);
        #pragma unroll
        for (int cb = 0; cb < 4; cb++) {
            int feat = cb * 16 + m;
            #pragma unroll
            for (int r = 0; r < 4; r++) {
                int row = quad * 4 + r;
                obuf[wv][row * 136 + feat] = f2bs(cz[cb][r]);
                obuf[wv][row * 136 + 64 + feat] = f2bs(cd[cb][r]);
            }
        }
        __builtin_amdgcn_wave_barrier();
        uint4* orow = (uint4*)(zsw + (long)n0 * 128);
        #pragma unroll
        for (int it = 0; it < 4; it++) {
            int idx = it * 64 + lane;
            int row = idx >> 4, ch = idx & 15;
            orow[(long)row * 16 + ch] = *(const uint4*)&obuf[wv][row * 136 + ch * 8];
        }
        __builtin_amdgcn_wave_barrier();
    }
}

// ---------------- merged: blocks 0-195 = CSR finalize, 196-963 = mmA ----------------
__global__ __launch_bounds__(256) void k4_mmA(const uint* __restrict__ bstore,
                                              const int* __restrict__ hist,
                                              const int* __restrict__ lsc,
                                              int* __restrict__ deg,
                                              float* __restrict__ dinv,
                                              int* __restrict__ row_end,
                                              int* __restrict__ csr_src,
                                              const bf16* __restrict__ x0,
                                              const bf16* __restrict__ sA,
                                              const void* __restrict__ W1,
                                              const void* __restrict__ Wg,
                                              const int* __restrict__ flags,
                                              bf16* __restrict__ zsw) {
    __shared__ __align__(16) char smem[44544];
    if (blockIdx.x < NBUCK) {
        k4_body(bstore, hist, lsc, deg, dinv, row_end, csr_src, blockIdx.x, smem);
    } else {
        mmA_body(x0, sA, W1, Wg, flags[0], zsw, blockIdx.x - NBUCK, 768, smem);
    }
}

// ---------------- mmB: x'=relu(hB@W2+b2) [LDS]; zsw=[x',s]@W1n | dinv*(s@Wgn) ----------------
__global__ __launch_bounds__(256) void k_mmB(const bf16* __restrict__ hB,
                                             const bf16* __restrict__ s,
                                             const void* __restrict__ W2,
                                             const void* __restrict__ B2,
                                             const void* __restrict__ W1n,
                                             const void* __restrict__ Wgn,
                                             const float* __restrict__ dinv,
                                             const int* __restrict__ flags,
                                             long w2_off, long b2_off, long w1n_off, long wgn_off,
                                             bf16* __restrict__ zsw) {
    __shared__ short wT2[64 * 72];
    __shared__ short wT1[64 * 136];
    __shared__ short wTg[64 * 72];
    __shared__ float bl2[64];
    __shared__ short buf[4][16 * 136];
    const int isf32 = flags[0];
    const int tid = threadIdx.x;
    for (int i = tid; i < 64 * 64; i += 256) {
        int k = i >> 6, f = i & 63;
        wT2[f * 72 + k] = f2bs(ldf(W2, w2_off + i, isf32));
        wTg[f * 72 + k] = f2bs(ldf(Wgn, wgn_off + i, isf32));
    }
    for (int i = tid; i < 64 * 128; i += 256) {
        int k = i >> 6, f = i & 63;
        wT1[f * 136 + k] = f2bs(ldf(W1n, w1n_off + i, isf32));
    }
    if (tid < 64) bl2[tid] = ldf(B2, b2_off + tid, isf32);
    __syncthreads();

    const int lane = tid & 63, wv = tid >> 6;
    const int m = lane & 15, quad = lane >> 4;

    short8 w2f[4][2], w1f[4][4];
    #pragma unroll
    for (int cb = 0; cb < 4; cb++) {
        #pragma unroll
        for (int ks = 0; ks < 2; ks++)
            w2f[cb][ks] = *(const short8*)&wT2[(cb * 16 + m) * 72 + ks * 32 + quad * 8];
        #pragma unroll
        for (int ks = 0; ks < 4; ks++)
            w1f[cb][ks] = *(const short8*)&wT1[(cb * 16 + m) * 136 + ks * 32 + quad * 8];
    }

    for (int t = blockIdx.x * 4 + wv; t < NTILES; t += gridDim.x * 4) {
        const int n0 = t * 16;
        {
            short8 ah[2];
            ah[0] = *(const short8*)&hB[(long)(n0 + m) * 64 + quad * 8];
            ah[1] = *(const short8*)&hB[(long)(n0 + m) * 64 + 32 + quad * 8];
            float4v cx[4];
            #pragma unroll
            for (int cb = 0; cb < 4; cb++) { cx[cb][0]=0.f; cx[cb][1]=0.f; cx[cb][2]=0.f; cx[cb][3]=0.f; }
            #pragma unroll
            for (int ks = 0; ks < 2; ks++)
                #pragma unroll
                for (int cb = 0; cb < 4; cb++)
                    cx[cb] = __builtin_amdgcn_mfma_f32_16x16x32_bf16(ah[ks], w2f[cb][ks], cx[cb], 0, 0, 0);
            #pragma unroll
            for (int cb = 0; cb < 4; cb++) {
                int feat = cb * 16 + m;
                float bb = bl2[feat];
                #pragma unroll
                for (int r = 0; r < 4; r++)
                    buf[wv][(quad * 4 + r) * 136 + feat] = f2bs(fmaxf(cx[cb][r] + bb, 0.f));
            }
        }
        __builtin_amdgcn_wave_barrier();
        short8 a[4];
        a[0] = *(const short8*)&buf[wv][m * 136 + quad * 8];
        a[1] = *(const short8*)&buf[wv][m * 136 + 32 + quad * 8];
        a[2] = *(const short8*)&s[(long)(n0 + m) * 64 + quad * 8];
        a[3] = *(const short8*)&s[(long)(n0 + m) * 64 + 32 + quad * 8];
        __builtin_amdgcn_wave_barrier();
        float4v cz[4], cd[4];
        #pragma unroll
        for (int cb = 0; cb < 4; cb++) {
            cz[cb][0]=0.f; cz[cb][1]=0.f; cz[cb][2]=0.f; cz[cb][3]=0.f;
            cd[cb][0]=0.f; cd[cb][1]=0.f; cd[cb][2]=0.f; cd[cb][3]=0.f;
        }
        #pragma unroll
        for (int ks = 0; ks < 4; ks++)
            #pragma unroll
            for (int cb = 0; cb < 4; cb++)
                cz[cb] = __builtin_amdgcn_mfma_f32_16x16x32_bf16(a[ks], w1f[cb][ks], cz[cb], 0, 0, 0);
        #pragma unroll
        for (int ks = 0; ks < 2; ks++)
            #pragma unroll
            for (int cb = 0; cb < 4; cb++) {
                short8 bg = *(const short8*)&wTg[(cb * 16 + m) * 72 + ks * 32 + quad * 8];
                cd[cb] = __builtin_amdgcn_mfma_f32_16x16x32_bf16(a[2 + ks], bg, cd[cb], 0, 0, 0);
            }
        #pragma unroll
        for (int cb = 0; cb < 4; cb++) {
            int feat = cb * 16 + m;
            #pragma unroll
            for (int r = 0; r < 4; r++) {
                int row = quad * 4 + r;
                buf[wv][row * 136 + feat] = f2bs(cz[cb][r]);
                buf[wv][row * 136 + 64 + feat] = f2bs(cd[cb][r] * dinv[n0 + row]);
            }
        }
        __builtin_amdgcn_wave_barrier();
        uint4* orow = (uint4*)(zsw + (long)n0 * 128);
        #pragma unroll
        for (int it = 0; it < 4; it++) {
            int idx = it * 64 + lane;
            int row = idx >> 4, ch = idx & 15;
            orow[(long)row * 16 + ch] = *(const uint4*)&buf[wv][row * 136 + ch * 8];
        }
        __builtin_amdgcn_wave_barrier();
    }
}

// ---------------- mmC (fused pool + FINAL): x'=relu(hB@W2+b2); w=[x',s]@Whp+bw; pool;
// last-8-ranked blocks (all 512 co-resident at 4/CU) spin on ctr, then do final. ----------------
__global__ __launch_bounds__(256) void k_mmC(const bf16* __restrict__ hB,
                                             const bf16* __restrict__ s,
                                             const void* __restrict__ W2,
                                             const void* __restrict__ B2,
                                             const void* __restrict__ Ww,
                                             const void* __restrict__ Bw,
                                             const int* __restrict__ batch,
                                             const int* __restrict__ flags,
                                             long w2_off, long b2_off,
                                             float* __restrict__ xp,
                                             int* __restrict__ ctr,
                                             const void* __restrict__ post_w,
                                             const void* __restrict__ post_b,
                                             const void* __restrict__ ro_w,
                                             const void* __restrict__ ro_b,
                                             void* __restrict__ out) {
    __shared__ short wT2[64 * 72];
    __shared__ short wTw[64 * 136];
    __shared__ float bl2[64], blw[64];
    __shared__ short xbuf[4][16 * 72];
    __shared__ int rank_s;
    const int isf32 = flags[0];
    const int i64 = flags[1];
    const int tid = threadIdx.x;
    for (int i = tid; i < 64 * 64; i += 256) {
        int k = i >> 6, f = i & 63;
        wT2[f * 72 + k] = f2bs(ldf(W2, w2_off + i, isf32));
    }
    for (int i = tid; i < 64 * 128; i += 256) {
        int k = i >> 6, f = i & 63;
        wTw[f * 136 + k] = f2bs(ldf(Ww, i, isf32));
    }
    if (tid < 64) { bl2[tid] = ldf(B2, b2_off + tid, isf32); blw[tid] = ldf(Bw, tid, isf32); }
    __syncthreads();

    const int lane = tid & 63, wv = tid >> 6;
    const int m = lane & 15, quad = lane >> 4;

    short8 w2f[4][2], wwf[4][4];
    float bwv[4];
    #pragma unroll
    for (int cb = 0; cb < 4; cb++) {
        #pragma unroll
        for (int ks = 0; ks < 2; ks++)
            w2f[cb][ks] = *(const short8*)&wT2[(cb * 16 + m) * 72 + ks * 32 + quad * 8];
        #pragma unroll
        for (int ks = 0; ks < 4; ks++)
            wwf[cb][ks] = *(const short8*)&wTw[(cb * 16 + m) * 136 + ks * 32 + quad * 8];
        bwv[cb] = blw[cb * 16 + m];
    }

    for (int t = blockIdx.x * 4 + wv; t < NTILES; t += gridDim.x * 4) {
        const int n0 = t * 16;
        {
            short8 ah[2];
            ah[0] = *(const short8*)&hB[(long)(n0 + m) * 64 + quad * 8];
            ah[1] = *(const short8*)&hB[(long)(n0 + m) * 64 + 32 + quad * 8];
            float4v cx[4];
            #pragma unroll
            for (int cb = 0; cb < 4; cb++) { cx[cb][0]=0.f; cx[cb][1]=0.f; cx[cb][2]=0.f; cx[cb][3]=0.f; }
            #pragma unroll
            for (int ks = 0; ks < 2; ks++)
                #pragma unroll
                for (int cb = 0; cb < 4; cb++)
                    cx[cb] = __builtin_amdgcn_mfma_f32_16x16x32_bf16(ah[ks], w2f[cb][ks], cx[cb], 0, 0, 0);
            #pragma unroll
            for (int cb = 0; cb < 4; cb++) {
                int feat = cb * 16 + m;
                float bb = bl2[feat];
                #pragma unroll
                for (int r = 0; r < 4; r++)
                    xbuf[wv][(quad * 4 + r) * 72 + feat] = f2bs(fmaxf(cx[cb][r] + bb, 0.f));
            }
        }
        __builtin_amdgcn_wave_barrier();
        {
            short8 a[4];
            a[0] = *(const short8*)&xbuf[wv][m * 72 + quad * 8];
            a[1] = *(const short8*)&xbuf[wv][m * 72 + 32 + quad * 8];
            a[2] = *(const short8*)&s[(long)(n0 + m) * 64 + quad * 8];
            a[3] = *(const short8*)&s[(long)(n0 + m) * 64 + 32 + quad * 8];
            float4v cz[4];
            #pragma unroll
            for (int cb = 0; cb < 4; cb++) { cz[cb][0]=0.f; cz[cb][1]=0.f; cz[cb][2]=0.f; cz[cb][3]=0.f; }
            #pragma unroll
            for (int ks = 0; ks < 4; ks++)
                #pragma unroll
                for (int cb = 0; cb < 4; cb++)
                    cz[cb] = __builtin_amdgcn_mfma_f32_16x16x32_bf16(a[ks], wwf[cb][ks], cz[cb], 0, 0, 0);

            int myb = geti(batch, n0 + (lane & 15), i64);
            float pacc[4];
            #pragma unroll
            for (int cb = 0; cb < 4; cb++) pacc[cb] = 0.f;
            int g = __shfl(myb, quad * 4);
            #pragma unroll
            for (int r = 0; r < 4; r++) {
                int gr = __shfl(myb, quad * 4 + r);
                if (gr != g) {
                    #pragma unroll
                    for (int cb = 0; cb < 4; cb++) {
                        atomicAdd(&xp[(long)g * 64 + cb * 16 + m], pacc[cb]);
                        pacc[cb] = 0.f;
                    }
                    g = gr;
                }
                #pragma unroll
                for (int cb = 0; cb < 4; cb++)
                    pacc[cb] += cz[cb][r] + bwv[cb];
            }
            #pragma unroll
            for (int cb = 0; cb < 4; cb++)
                atomicAdd(&xp[(long)g * 64 + cb * 16 + m], pacc[cb]);
        }
        __builtin_amdgcn_wave_barrier();
    }

    // ---- rank handshake; last 8 blocks do post+readout+log_softmax ----
    __syncthreads();
    if (tid == 0) {
        __threadfence();
        rank_s = atomicAdd(ctr, 1);
    }
    __syncthreads();
    int rank = rank_s;
    int total = (int)gridDim.x;
    if (rank >= total - 8) {
        if (tid == 0) {
            while (__hip_atomic_load(ctr, __ATOMIC_ACQUIRE, __HIP_MEMORY_SCOPE_AGENT) < total)
                __builtin_amdgcn_s_sleep(2);
        }
        __syncthreads();
        __threadfence();
        int slot = rank - (total - 8);           // 0..7 -> 64 graphs each
        int f = tid & 63, w = tid >> 6;          // 4 waves, 1 graph per wave per iter
        for (int it = 0; it < 16; it++) {
            int g = slot * 64 + it * 4 + w;
            float xr = __hip_atomic_load(&xp[(long)g * 64 + f], __ATOMIC_RELAXED, __HIP_MEMORY_SCOPE_AGENT);
            float acc = ldf(post_b, f, isf32);
            #pragma unroll
            for (int j = 0; j < 64; j++) acc += __shfl(xr, j) * ldf(post_w, j * 64 + f, isf32);
            float v = fmaxf(acc, 0.f);
            long oxp = (long)g * 64 + f;
            if (isf32) ((float*)out)[oxp] = v; else ((bf16*)out)[oxp] = f2b(v);
            float aa = (f < 16) ? ldf(ro_b, f, isf32) : 0.f;
            #pragma unroll
            for (int j = 0; j < 64; j++) {
                float vj = __shfl(v, j);
                if (f < 16) aa += vj * ldf(ro_w, j * 16 + f, isf32);
            }
            if (f < 16) {
                float mm = -1e30f;
                for (int j = 0; j < 16; j++) mm = fmaxf(mm, __shfl(aa, j));
                float sum = 0.f;
                for (int j = 0; j < 16; j++) sum += expf(__shfl(aa, j) - mm);
                long oy = (long)N_GRAPHS * 64 + (long)g * 16 + f;
                float yv = aa - mm - logf(sum);
                if (isf32) ((float*)out)[oy] = yv; else ((bf16*)out)[oy] = f2b(yv);
            }
        }
    }
}

// ---------------- fused GIN+GCN gather. DV=1: per-source dinv via FMA (layer 0);
// DV=0: plain adds, zsw GCN half pre-scaled by producer (layer 1). ----------------
template <int DV>
__global__ __launch_bounds__(256) void k_gather4(const uint* __restrict__ zsw,
                                                 const int* __restrict__ row_end,
                                                 const int* __restrict__ deg,
                                                 const int* __restrict__ csr_src,
                                                 const void* __restrict__ b1,
                                                 const void* __restrict__ bg,
                                                 const float* __restrict__ dinv,
                                                 const int* __restrict__ flags,
                                                 long b_off,
                                                 uint* __restrict__ hB,
                                                 uint* __restrict__ sOut) {
    int tid = threadIdx.x;
    int wv = tid >> 6, lane = tid & 63;
    int grp = lane >> 4, sub = lane & 15;
    int n = blockIdx.x * 4 + wv;
    if (n >= N_NODES) return;
    int end = row_end[n], dg = deg[n];
    int beg = end - dg;
    int R = dg + 1;
    int myidx = n;
    if (lane > 0 && lane <= dg && lane < 64)
        myidx = __builtin_nontemporal_load(&csr_src[beg + lane - 1]);
    float mydinv = DV ? dinv[myidx] : 0.f;
    const bool ginhalf = (sub < 8);
    const uint4* zp = (const uint4*)zsw;
    float a[8];
    #pragma unroll
    for (int j = 0; j < 8; j++) a[j] = 0.f;
    int Rm = (R < 64) ? R : 64;
    {
        int r0 = grp, r1 = 4 + grp, r2 = 8 + grp, r3 = 12 + grp;
        int s0 = __shfl(myidx, r0), s1 = __shfl(myidx, r1),
            s2 = __shfl(myidx, r2), s3 = __shfl(myidx, r3);
        uint4 u0 = {0,0,0,0}, u1 = {0,0,0,0}, u2 = {0,0,0,0}, u3 = {0,0,0,0};
        if (r0 < Rm) u0 = zp[(long)s0 * 16 + sub];
        if (r1 < Rm) u1 = zp[(long)s1 * 16 + sub];
        if (r2 < Rm) u2 = zp[(long)s2 * 16 + sub];
        if (r3 < Rm) u3 = zp[(long)s3 * 16 + sub];
        if constexpr (DV) {
            float d0 = __shfl(mydinv, r0), d1 = __shfl(mydinv, r1),
                  d2 = __shfl(mydinv, r2), d3 = __shfl(mydinv, r3);
            float c0 = ginhalf ? 1.f : d0, c1 = ginhalf ? 1.f : d1,
                  c2 = ginhalf ? 1.f : d2, c3 = ginhalf ? 1.f : d3;
            a[0] = fmaf(c0, bflo(u0.x), fmaf(c1, bflo(u1.x), fmaf(c2, bflo(u2.x), fmaf(c3, bflo(u3.x), a[0]))));
            a[1] = fmaf(c0, bfhi(u0.x), fmaf(c1, bfhi(u1.x), fmaf(c2, bfhi(u2.x), fmaf(c3, bfhi(u3.x), a[1]))));
            a[2] = fmaf(c0, bflo(u0.y), fmaf(c1, bflo(u1.y), fmaf(c2, bflo(u2.y), fmaf(c3, bflo(u3.y), a[2]))));
            a[3] = fmaf(c0, bfhi(u0.y), fmaf(c1, bfhi(u1.y), fmaf(c2, bfhi(u2.y), fmaf(c3, bfhi(u3.y), a[3]))));
            a[4] = fmaf(c0, bflo(u0.z), fmaf(c1, bflo(u1.z), fmaf(c2, bflo(u2.z), fmaf(c3, bflo(u3.z), a[4]))));
            a[5] = fmaf(c0, bfhi(u0.z), fmaf(c1, bfhi(u1.z), fmaf(c2, bfhi(u2.z), fmaf(c3, bfhi(u3.z), a[5]))));
            a[6] = fmaf(c0, bflo(u0.w), fmaf(c1, bflo(u1.w), fmaf(c2, bflo(u2.w), fmaf(c3, bflo(u3.w), a[6]))));
            a[7] = fmaf(c0, bfhi(u0.w), fmaf(c1, bfhi(u1.w), fmaf(c2, bfhi(u2.w), fmaf(c3, bfhi(u3.w), a[7]))));
        } else {
            a[0] += (bflo(u0.x) + bflo(u1.x)) + (bflo(u2.x) + bflo(u3.x));
            a[1] += (bfhi(u0.x) + bfhi(u1.x)) + (bfhi(u2.x) + bfhi(u3.x));
            a[2] += (bflo(u0.y) + bflo(u1.y)) + (bflo(u2.y) + bflo(u3.y));
            a[3] += (bfhi(u0.y) + bfhi(u1.y)) + (bfhi(u2.y) + bfhi(u3.y));
            a[4] += (bflo(u0.z) + bflo(u1.z)) + (bflo(u2.z) + bflo(u3.z));
            a[5] += (bfhi(u0.z) + bfhi(u1.z)) + (bfhi(u2.z) + bfhi(u3.z));
            a[6] += (bflo(u0.w) + bflo(u1.w)) + (bflo(u2.w) + bflo(u3.w));
            a[7] += (bfhi(u0.w) + bfhi(u1.w)) + (bfhi(u2.w) + bfhi(u3.w));
        }
    }
    for (int i = 16; i < Rm; i += 4) {
        int r = i + grp;
        int sr = __shfl(myidx, r);
        uint4 u = {0,0,0,0};
        if (r < Rm) u = zp[(long)sr * 16 + sub];
        if constexpr (DV) {
            float dr = __shfl(mydinv, r);
            float cc = ginhalf ? 1.f : dr;
            a[0] = fmaf(cc, bflo(u.x), a[0]); a[1] = fmaf(cc, bfhi(u.x), a[1]);
            a[2] = fmaf(cc, bflo(u.y), a[2]); a[3] = fmaf(cc, bfhi(u.y), a[3]);
            a[4] = fmaf(cc, bflo(u.z), a[4]); a[5] = fmaf(cc, bfhi(u.z), a[5]);
            a[6] = fmaf(cc, bflo(u.w), a[6]); a[7] = fmaf(cc, bfhi(u.w), a[7]);
        } else {
            a[0] += bflo(u.x); a[1] += bfhi(u.x);
            a[2] += bflo(u.y); a[3] += bfhi(u.y);
            a[4] += bflo(u.z); a[5] += bfhi(u.z);
            a[6] += bflo(u.w); a[7] += bfhi(u.w);
        }
    }
    // rare tail for deg > 63 (correctness only)
    for (int i = 64; i < R; i += 8) {
        int iA = i + grp, iB = i + 4 + grp;
        uint4 uA = {0,0,0,0}, uB = {0,0,0,0};
        float cA = 1.f, cB = 1.f;
        if (iA < R) {
            int sA = __builtin_nontemporal_load(&csr_src[beg + iA - 1]);
            uA = zp[(long)sA * 16 + sub];
            if (DV && !ginhalf) cA = dinv[sA];
        }
        if (iB < R) {
            int sB = __builtin_nontemporal_load(&csr_src[beg + iB - 1]);
            uB = zp[(long)sB * 16 + sub];
            if (DV && !ginhalf) cB = dinv[sB];
        }
        a[0] = fmaf(cA, bflo(uA.x), fmaf(cB, bflo(uB.x), a[0]));
        a[1] = fmaf(cA, bfhi(uA.x), fmaf(cB, bfhi(uB.x), a[1]));
        a[2] = fmaf(cA, bflo(uA.y), fmaf(cB, bflo(uB.y), a[2]));
        a[3] = fmaf(cA, bfhi(uA.y), fmaf(cB, bfhi(uB.y), a[3]));
        a[4] = fmaf(cA, bflo(uA.z), fmaf(cB, bflo(uB.z), a[4]));
        a[5] = fmaf(cA, bfhi(uA.z), fmaf(cB, bfhi(uB.z), a[5]));
        a[6] = fmaf(cA, bflo(uA.w), fmaf(cB, bflo(uB.w), a[6]));
        a[7] = fmaf(cA, bfhi(uA.w), fmaf(cB, bfhi(uB.w), a[7]));
    }
    #pragma unroll
    for (int j = 0; j < 8; j++) {
        a[j] += __shfl_xor(a[j], 16);
        a[j] += __shfl_xor(a[j], 32);
    }
    int q = 4 * sub + grp;
    float v0 = a[2 * grp], v1 = a[2 * grp + 1];
    int isf32 = flags[0];
    if (q < 32) {
        float c0 = ldf(b1, b_off + 2 * q, isf32);
        float c1 = ldf(b1, b_off + 2 * q + 1, isf32);
        hB[(long)n * 32 + q] = packbf(fmaxf(v0 + c0, 0.f), fmaxf(v1 + c1, 0.f));
    } else {
        int qq = q - 32;
        float c0 = ldf(bg, b_off + 2 * qq, isf32);
        float c1 = ldf(bg, b_off + 2 * qq + 1, isf32);
        float dn = dinv[n];
        sOut[(long)n * 32 + qq] = packbf(tanhfast(dn * v0 + c0), tanhfast(dn * v1 + c1));
    }
}

extern "C" void kernel_launch(void* const* d_in, const int* in_sizes, int n_in,
                              void* d_out, int out_size, void* d_ws, size_t ws_size,
                              hipStream_t stream) {
    const void* x_in  = d_in[0];
    const void* s_in  = d_in[1];
    const int*  ei    = (const int*)d_in[2];
    const int*  batch = (const int*)d_in[3];
    const void* pre_w = d_in[4];
    const void* pre_b = d_in[5];
    const void* emb_w = d_in[6];
    const void* emb_b = d_in[7];
    const void* gin_w1 = d_in[8];
    const void* gin_b1 = d_in[9];
    const void* gin_w2 = d_in[10];
    const void* gin_b2 = d_in[11];
    const void* gcn_w  = d_in[12];
    const void* gcn_b  = d_in[13];
    const void* whp_w  = d_in[14];
    const void* whp_b  = d_in[15];
    const void* post_w = d_in[16];
    const void* post_b = d_in[17];
    const void* ro_w   = d_in[18];
    const void* ro_b   = d_in[19];

    int* flags   = (int*)d_ws;
    int* deg     = flags + 64;
    int* row_end = deg + N_NODES;
    int* hist    = row_end + N_NODES;          // [NBUCK][256]
    int* lsc     = hist + 256 * NBUCK;         // [NBUCK][256]
    uint* bstore = (uint*)(lsc + 256 * NBUCK); // [256][BST]
    int* csr_src = (int*)(bstore + (long)256 * BST);
    float* dinv  = (float*)(csr_src + N_EDGES);
    bf16* x0     = (bf16*)(dinv + N_NODES);
    bf16* sA     = x0 + (long)N_NODES * 64;
    bf16* hB     = sA + (long)N_NODES * 64;
    uint* zsw    = (uint*)(hB + (long)N_NODES * 64);
    float* xp    = (float*)(zsw + (long)N_NODES * 64);
    int* ctr     = flags + 8;

    const int GGB = (N_NODES + 3) / 4;       // 25000

    // front: detect + CSR partition + pre/emb GEMM + xp/ctr zero, one overlapped dispatch
    k_front<<<897, 256, 0, stream>>>(ei, x_in, pre_w, pre_b, s_in, emb_w, emb_b,
                                     bstore, hist, lsc, flags, x0, sA, xp);

    const long W1 = 128 * 64, W2 = 64 * 64, WG = 64 * 64, B = 64;

    // ---- CSR finalize + layer-0 GEMM merged (k4 blocks first) ----
    k4_mmA<<<NBUCK + 768, 256, 0, stream>>>(bstore, hist, lsc, deg, dinv, row_end, csr_src,
                                            x0, sA, gin_w1, gcn_w, flags, (bf16*)zsw);
    k_gather4<1><<<GGB, 256, 0, stream>>>(zsw, row_end, deg, csr_src, gin_b1, gcn_b, dinv, flags, 0L, (uint*)hB, (uint*)sA);

    // ---- layer 0 tail fused with layer 1 head (GCN half pre-scaled by dinv) ----
    k_mmB<<<512, 256, 0, stream>>>(hB, sA, gin_w2, gin_b2, gin_w1, gcn_w, dinv, flags,
                                   0L, 0L, W1, WG, (bf16*)zsw);
    k_gather4<0><<<GGB, 256, 0, stream>>>(zsw, row_end, deg, csr_src, gin_b1, gcn_b, dinv, flags, B, (uint*)hB, (uint*)sA);

    // ---- layer 1 tail + whp + pool + final fused (last-8-blocks pattern) ----
    k_mmC<<<512, 256, 0, stream>>>(hB, sA, gin_w2, gin_b2, whp_w, whp_b, batch, flags, W2, B,
                                   xp, ctr, post_w, post_b, ro_w, ro_b, d_out);
}

// Round 11
// 448.684 us; speedup vs baseline: 1.2885x; 1.2885x over previous
//
#include <hip/hip_runtime.h>
#include <hip/hip_bf16.h>

#define N_NODES 100000
#define N_EDGES 1600000
#define N_GRAPHS 512
#define NTILES (N_NODES / 16)          // 6250, exact
#define BSH 9                          // 512 nodes per bucket
#define NBUCK ((N_NODES + 511) >> BSH) // 196
#define NB1 256                        // partition blocks
#define BST 6400                       // per-block bstore stride (max edges/block)

typedef __hip_bfloat16 bf16;
typedef unsigned int uint;
typedef unsigned short ushort;
typedef __attribute__((ext_vector_type(8))) short short8;
typedef __attribute__((ext_vector_type(4))) float float4v;
typedef __attribute__((ext_vector_type(2))) int int2v;

__device__ __forceinline__ float b2f(bf16 v) { return __bfloat162float(v); }
__device__ __forceinline__ bf16 f2b(float v) { return __float2bfloat16(v); }
__device__ __forceinline__ short f2bs(float v) { bf16 h = f2b(v); return *(short*)&h; }

__device__ __forceinline__ float ldf(const void* p, long i, int isf32) {
    return isf32 ? ((const float*)p)[i] : b2f(((const bf16*)p)[i]);
}
__device__ __forceinline__ int geti(const int* p, long i, int is64) {
    return is64 ? ((const int2v*)p)[i].x : p[i];
}
__device__ __forceinline__ float bflo(uint u) { return __uint_as_float(u << 16); }
__device__ __forceinline__ float bfhi(uint u) { return __uint_as_float(u & 0xffff0000u); }
__device__ __forceinline__ uint packbf(float x, float y) {
    bf16 a = f2b(x), b = f2b(y);
    ushort ua = *(ushort*)&a, ub = *(ushort*)&b;
    return (uint)ua | ((uint)ub << 16);
}
// fast tanh: clamp + exp ratio; |err| ~1e-6, far below bf16 rounding
__device__ __forceinline__ float tanhfast(float x) {
    float xc = fminf(fmaxf(x, -15.f), 15.f);
    float e = __expf(2.f * xc);
    return __fdividef(e - 1.f, e + 1.f);
}

// ---------------- MFMA input linear body (pre / emb) ----------------
template <int K, int KA>
__device__ __forceinline__ void mm_in_body(const void* __restrict__ A0,
                                           const void* __restrict__ W,
                                           const void* __restrict__ Bv,
                                           int isf32, bf16* __restrict__ outp,
                                           short* wT, float* bl, short (*obuf)[16 * 72],
                                           int bid, int nb) {
    const int tid = threadIdx.x;
    for (int i = tid; i < 64 * K; i += 256) {
        int k = i >> 6, f = i & 63;
        float v = (k < KA) ? ldf(W, i, isf32) : 0.f;
        wT[f * (K + 8) + k] = f2bs(v);
    }
    if (tid < 64) bl[tid] = ldf(Bv, tid, isf32);
    __syncthreads();

    const int lane = tid & 63, wv = tid >> 6;
    const int m = lane & 15, quad = lane >> 4;

    short8 bfr[4][K / 32];
    #pragma unroll
    for (int cb = 0; cb < 4; cb++)
        #pragma unroll
        for (int ks = 0; ks < K / 32; ks++)
            bfr[cb][ks] = *(const short8*)&wT[(cb * 16 + m) * (K + 8) + ks * 32 + quad * 8];

    for (int t = bid * 4 + wv; t < NTILES; t += nb * 4) {
        const int n0 = t * 16;
        short8 af[K / 32];
        if (isf32) {
            const float* Af = (const float*)A0 + (long)(n0 + m) * KA;
            #pragma unroll
            for (int ks = 0; ks < K / 32; ks++) {
                short8 a;
                #pragma unroll
                for (int j = 0; j < 8; j++) {
                    int k = ks * 32 + quad * 8 + j;
                    float v = (KA % 32 == 0 || k < KA) ? Af[k] : 0.f;
                    a[j] = f2bs(v);
                }
                af[ks] = a;
            }
        } else {
            const bf16* Ab = (const bf16*)A0 + (long)(n0 + m) * KA;
            #pragma unroll
            for (int ks = 0; ks < K / 32; ks++) {
                if constexpr (KA % 32 == 0) {
                    af[ks] = *(const short8*)&Ab[ks * 32 + quad * 8];
                } else {
                    short8 a;
                    #pragma unroll
                    for (int j = 0; j < 8; j++) {
                        int k = ks * 32 + quad * 8 + j;
                        float v = (k < KA) ? b2f(Ab[k]) : 0.f;
                        a[j] = f2bs(v);
                    }
                    af[ks] = a;
                }
            }
        }
        float4v c[4];
        #pragma unroll
        for (int cb = 0; cb < 4; cb++) { c[cb][0]=0.f; c[cb][1]=0.f; c[cb][2]=0.f; c[cb][3]=0.f; }
        #pragma unroll
        for (int ks = 0; ks < K / 32; ks++)
            #pragma unroll
            for (int cb = 0; cb < 4; cb++)
                c[cb] = __builtin_amdgcn_mfma_f32_16x16x32_bf16(af[ks], bfr[cb][ks], c[cb], 0, 0, 0);
        #pragma unroll
        for (int cb = 0; cb < 4; cb++) {
            int feat = cb * 16 + m;
            #pragma unroll
            for (int r = 0; r < 4; r++)
                obuf[wv][(quad * 4 + r) * 72 + feat] = f2bs(c[cb][r] + bl[feat]);
        }
        __builtin_amdgcn_wave_barrier();
        uint4* orow = (uint4*)(outp + (long)n0 * 64);
        #pragma unroll
        for (int it = 0; it < 2; it++) {
            int idx = it * 64 + lane;
            int row = idx >> 3, ch = idx & 7;
            orow[(long)row * 8 + ch] = *(const uint4*)&obuf[wv][row * 72 + ch * 8];
        }
        __builtin_amdgcn_wave_barrier();
    }
}

// ---------------- k_front: detect + CSR partition + pre/emb GEMM + xp zero ----------------
__global__ __launch_bounds__(256) void k_front(const int* __restrict__ ei,
                                               const void* __restrict__ x_in,
                                               const void* __restrict__ pre_w,
                                               const void* __restrict__ pre_b,
                                               const void* __restrict__ s_in,
                                               const void* __restrict__ emb_w,
                                               const void* __restrict__ emb_b,
                                               uint* __restrict__ bstore,
                                               int* __restrict__ hist,
                                               int* __restrict__ lsc,
                                               int* __restrict__ flags,
                                               bf16* __restrict__ x0,
                                               bf16* __restrict__ sA,
                                               float* __restrict__ xp) {
    __shared__ __align__(16) char smem[28672];
    __shared__ int fl[2];
    const int tid = threadIdx.x;
    if (tid == 0) { fl[0] = 0; fl[1] = 0; }
    __syncthreads();
    {
        const ushort* xu = (const ushort*)x_in;
        ushort u = xu[2 * tid];
        int e = (u >> 7) & 0xFF;
        int plaus = (u == 0 || (e >= 116 && e <= 132)) ? 1 : 0;
        int nz = (tid < 128 && ei[2 * tid + 1] != 0) ? 1 : 0;
        atomicAdd(&fl[0], plaus);
        atomicAdd(&fl[1], nz);
    }
    __syncthreads();
    const int isf32 = (fl[0] < 128) ? 1 : 0;
    const int i64 = (fl[1] < 8) ? 1 : 0;
    const int bb = blockIdx.x;

    if (bb == 896) {
        if (tid == 0) { flags[0] = isf32; flags[1] = i64; }
        for (int i = tid; i < N_GRAPHS * 64; i += 256) xp[i] = 0.f;
        return;
    }
    if (bb < 256) {
        // ---- CSR partition ----
        int* lh = (int*)smem;              // 256 (NBUCK used)
        int* lpos = lh + 256;              // 256
        int* tmp = lpos + 256;             // 256
        uint* stage = (uint*)(tmp + 256);  // 6400
        int b = bb, t = tid;
        for (int i = t; i < NBUCK; i += 256) lh[i] = 0;
        __syncthreads();
        int rk[25], ck[25];
        #pragma unroll
        for (int k = 0; k < 25; k++) {
            int e = k * (NB1 * 256) + b * 256 + t;
            int r = 0, c = -1;
            if (e < N_EDGES) {
                r = geti(ei, e, i64);
                c = geti(ei, (long)N_EDGES + e, i64);
                atomicAdd(&lh[c >> BSH], 1);
            }
            rk[k] = r; ck[k] = c;
        }
        __syncthreads();
        int v = (t < NBUCK) ? lh[t] : 0;
        tmp[t] = v;
        __syncthreads();
        for (int off = 1; off < 256; off <<= 1) {
            int u = (t >= off) ? tmp[t - off] : 0;
            __syncthreads();
            tmp[t] += u;
            __syncthreads();
        }
        if (t < NBUCK) {
            int excl = tmp[t] - v;
            lsc[(long)t * 256 + b] = excl;
            hist[(long)t * 256 + b] = v;
            lpos[t] = excl;
        }
        __syncthreads();
        #pragma unroll
        for (int k = 0; k < 25; k++) {
            int c = ck[k];
            if (c >= 0) {
                int p = atomicAdd(&lpos[c >> BSH], 1);
                stage[p] = ((uint)rk[k] << BSH) | (uint)(c & 511);
            }
        }
        __syncthreads();
        int cnt_all = tmp[255];
        uint* dst = bstore + (long)b * BST;
        for (int i = t; i < cnt_all; i += 256) dst[i] = stage[i];
    } else {
        short* wT = (short*)smem;                              // 64*136 shorts
        float* bl = (float*)(smem + 64 * 136 * 2);             // 64 floats
        short (*obuf)[16 * 72] = (short (*)[16 * 72])(smem + 64 * 136 * 2 + 256);
        if (bb < 768)
            mm_in_body<128, 128>(x_in, pre_w, pre_b, isf32, x0, wT, bl, obuf, bb - 256, 512);
        else
            mm_in_body<32, 16>(s_in, emb_w, emb_b, isf32, sA, wT, bl, obuf, bb - 768, 128);
    }
}

// ---------------- k4 body: CSR finalize (bucket totals row-summed from hist) ----------------
__device__ __forceinline__ void k4_body(const uint* __restrict__ bstore,
                                        const int* __restrict__ hist,
                                        const int* __restrict__ lsc,
                                        int* __restrict__ deg,
                                        float* __restrict__ dinv,
                                        int* __restrict__ row_end,
                                        int* __restrict__ csr_src,
                                        int B, char* smem) {
    int* cnt   = (int*)smem;        // 512
    int* exc   = cnt + 512;         // 512
    int* tmp   = exc + 512;         // 256
    int* slen  = tmp + 256;         // 256
    int* sbase = slen + 256;        // 256
    int* bb_sp = sbase + 256;       // 1
    int t = threadIdx.x;
    cnt[t] = 0; cnt[t + 256] = 0;
    slen[t] = hist[(long)B * 256 + t];
    sbase[t] = t * BST + lsc[(long)B * 256 + t];
    // bucket total[t] = sum over all 256 partition blocks of hist[t][b]
    int v0 = 0;
    if (t < NBUCK) {
        const int4* hp = (const int4*)(hist + (long)t * 256);
        #pragma unroll 8
        for (int i = 0; i < 64; i++) { int4 h4 = hp[i]; v0 += h4.x + h4.y + h4.z + h4.w; }
    }
    tmp[t] = v0;
    __syncthreads();
    for (int off = 1; off < 256; off <<= 1) {
        int u = (t >= off) ? tmp[t - off] : 0;
        __syncthreads();
        tmp[t] += u;
        __syncthreads();
    }
    if (t == B) bb_sp[0] = tmp[t] - v0;
    __syncthreads();
    int wv = t >> 6, lane = t & 63;
    for (int j = wv; j < 256; j += 4) {
        int len = slen[j];
        const uint* src = bstore + sbase[j];
        for (int i = lane; i < len; i += 64) atomicAdd(&cnt[src[i] & 511], 1);
    }
    __syncthreads();
    int c0 = cnt[2 * t], c1 = cnt[2 * t + 1];
    tmp[t] = c0 + c1;
    __syncthreads();
    for (int off = 1; off < 256; off <<= 1) {
        int u = (t >= off) ? tmp[t - off] : 0;
        __syncthreads();
        tmp[t] += u;
        __syncthreads();
    }
    int ep = tmp[t] - (c0 + c1);
    exc[2 * t] = ep;
    exc[2 * t + 1] = ep + c0;
    int bb = bb_sp[0];
    int n0 = (B << BSH) + 2 * t;
    if (n0 < N_NODES) {
        deg[n0] = c0;
        dinv[n0] = rsqrtf((float)c0 + 1.0f);
        row_end[n0] = bb + ep + c0;
    }
    if (n0 + 1 < N_NODES) {
        deg[n0 + 1] = c1;
        dinv[n0 + 1] = rsqrtf((float)c1 + 1.0f);
        row_end[n0 + 1] = bb + ep + c0 + c1;
    }
    __syncthreads();
    for (int j = wv; j < 256; j += 4) {
        int len = slen[j];
        const uint* src = bstore + sbase[j];
        for (int i = lane; i < len; i += 64) {
            uint p = src[i];
            int pos = atomicAdd(&exc[p & 511], 1);
            csr_src[bb + pos] = (int)(p >> BSH);
        }
    }
}

// ---------------- mmA body: zsw row = [x,s]@W1 | s@Wg (GCN half UNSCALED;
// dinv applied per-source in gather DV=1) ----------------
__device__ __forceinline__ void mmA_body(const bf16* __restrict__ x,
                                         const bf16* __restrict__ s,
                                         const void* __restrict__ W1,
                                         const void* __restrict__ Wg,
                                         int isf32, bf16* __restrict__ zsw,
                                         int bid, int nb, char* smem) {
    short* wT1 = (short*)smem;                       // 64*136
    short* wTg = wT1 + 64 * 136;                     // 64*72
    short (*obuf)[16 * 136] = (short (*)[16 * 136])(wTg + 64 * 72);
    const int tid = threadIdx.x;
    for (int i = tid; i < 64 * 128; i += 256) {
        int k = i >> 6, f = i & 63;
        wT1[f * 136 + k] = f2bs(ldf(W1, i, isf32));
    }
    for (int i = tid; i < 64 * 64; i += 256) {
        int k = i >> 6, f = i & 63;
        wTg[f * 72 + k] = f2bs(ldf(Wg, i, isf32));
    }
    __syncthreads();

    const int lane = tid & 63, wv = tid >> 6;
    const int m = lane & 15, quad = lane >> 4;

    short8 w1f[4][4], wgf[4][2];
    #pragma unroll
    for (int cb = 0; cb < 4; cb++) {
        #pragma unroll
        for (int ks = 0; ks < 4; ks++)
            w1f[cb][ks] = *(const short8*)&wT1[(cb * 16 + m) * 136 + ks * 32 + quad * 8];
        #pragma unroll
        for (int ks = 0; ks < 2; ks++)
            wgf[cb][ks] = *(const short8*)&wTg[(cb * 16 + m) * 72 + ks * 32 + quad * 8];
    }

    for (int t = bid * 4 + wv; t < NTILES; t += nb * 4) {
        const int n0 = t * 16;
        short8 a[4];
        a[0] = *(const short8*)&x[(long)(n0 + m) * 64 + quad * 8];
        a[1] = *(const short8*)&x[(long)(n0 + m) * 64 + 32 + quad * 8];
        a[2] = *(const short8*)&s[(long)(n0 + m) * 64 + quad * 8];
        a[3] = *(const short8*)&s[(long)(n0 + m) * 64 + 32 + quad * 8];
        float4v cz[4], cd[4];
        #pragma unroll
        for (int cb = 0; cb < 4; cb++) {
            cz[cb][0]=0.f; cz[cb][1]=0.f; cz[cb][2]=0.f; cz[cb][3]=0.f;
            cd[cb][0]=0.f; cd[cb][1]=0.f; cd[cb][2]=0.f; cd[cb][3]=0.f;
        }
        #pragma unroll
        for (int ks = 0; ks < 4; ks++)
            #pragma unroll
            for (int cb = 0; cb < 4; cb++)
                cz[cb] = __builtin_amdgcn_mfma_f32_16x16x32_bf16(a[ks], w1f[cb][ks], cz[cb], 0, 0, 0);
        #pragma unroll
        for (int ks = 0; ks < 2; ks++)
            #pragma unroll
            for (int cb = 0; cb < 4; cb++)
                cd[cb] = __builtin_amdgcn_mfma_f32_16x16x32_bf16(a[2 + ks], wgf[cb][ks], cd[cb], 0, 0, 0);
        #pragma unroll
        for (int cb = 0; cb < 4; cb++) {
            int feat = cb * 16 + m;
            #pragma unroll
            for (int r = 0; r < 4; r++) {
                int row = quad * 4 + r;
                obuf[wv][row * 136 + feat] = f2bs(cz[cb][r]);
                obuf[wv][row * 136 + 64 + feat] = f2bs(cd[cb][r]);
            }
        }
        __builtin_amdgcn_wave_barrier();
        uint4* orow = (uint4*)(zsw + (long)n0 * 128);
        #pragma unroll
        for (int it = 0; it < 4; it++) {
            int idx = it * 64 + lane;
            int row = idx >> 4, ch = idx & 15;
            orow[(long)row * 16 + ch] = *(const uint4*)&obuf[wv][row * 136 + ch * 8];
        }
        __builtin_amdgcn_wave_barrier();
    }
}

// ---------------- merged: blocks 0-195 = CSR finalize, 196-963 = mmA ----------------
__global__ __launch_bounds__(256) void k4_mmA(const uint* __restrict__ bstore,
                                              const int* __restrict__ hist,
                                              const int* __restrict__ lsc,
                                              int* __restrict__ deg,
                                              float* __restrict__ dinv,
                                              int* __restrict__ row_end,
                                              int* __restrict__ csr_src,
                                              const bf16* __restrict__ x0,
                                              const bf16* __restrict__ sA,
                                              const void* __restrict__ W1,
                                              const void* __restrict__ Wg,
                                              const int* __restrict__ flags,
                                              bf16* __restrict__ zsw) {
    __shared__ __align__(16) char smem[44544];
    if (blockIdx.x < NBUCK) {
        k4_body(bstore, hist, lsc, deg, dinv, row_end, csr_src, blockIdx.x, smem);
    } else {
        mmA_body(x0, sA, W1, Wg, flags[0], zsw, blockIdx.x - NBUCK, 768, smem);
    }
}

// ---------------- mmB: x'=relu(hB@W2+b2) [LDS]; zsw=[x',s]@W1n | dinv*(s@Wgn) ----------------
__global__ __launch_bounds__(256) void k_mmB(const bf16* __restrict__ hB,
                                             const bf16* __restrict__ s,
                                             const void* __restrict__ W2,
                                             const void* __restrict__ B2,
                                             const void* __restrict__ W1n,
                                             const void* __restrict__ Wgn,
                                             const float* __restrict__ dinv,
                                             const int* __restrict__ flags,
                                             long w2_off, long b2_off, long w1n_off, long wgn_off,
                                             bf16* __restrict__ zsw) {
    __shared__ short wT2[64 * 72];
    __shared__ short wT1[64 * 136];
    __shared__ short wTg[64 * 72];
    __shared__ float bl2[64];
    __shared__ short buf[4][16 * 136];
    const int isf32 = flags[0];
    const int tid = threadIdx.x;
    for (int i = tid; i < 64 * 64; i += 256) {
        int k = i >> 6, f = i & 63;
        wT2[f * 72 + k] = f2bs(ldf(W2, w2_off + i, isf32));
        wTg[f * 72 + k] = f2bs(ldf(Wgn, wgn_off + i, isf32));
    }
    for (int i = tid; i < 64 * 128; i += 256) {
        int k = i >> 6, f = i & 63;
        wT1[f * 136 + k] = f2bs(ldf(W1n, w1n_off + i, isf32));
    }
    if (tid < 64) bl2[tid] = ldf(B2, b2_off + tid, isf32);
    __syncthreads();

    const int lane = tid & 63, wv = tid >> 6;
    const int m = lane & 15, quad = lane >> 4;

    short8 w2f[4][2], w1f[4][4];
    #pragma unroll
    for (int cb = 0; cb < 4; cb++) {
        #pragma unroll
        for (int ks = 0; ks < 2; ks++)
            w2f[cb][ks] = *(const short8*)&wT2[(cb * 16 + m) * 72 + ks * 32 + quad * 8];
        #pragma unroll
        for (int ks = 0; ks < 4; ks++)
            w1f[cb][ks] = *(const short8*)&wT1[(cb * 16 + m) * 136 + ks * 32 + quad * 8];
    }

    for (int t = blockIdx.x * 4 + wv; t < NTILES; t += gridDim.x * 4) {
        const int n0 = t * 16;
        {
            short8 ah[2];
            ah[0] = *(const short8*)&hB[(long)(n0 + m) * 64 + quad * 8];
            ah[1] = *(const short8*)&hB[(long)(n0 + m) * 64 + 32 + quad * 8];
            float4v cx[4];
            #pragma unroll
            for (int cb = 0; cb < 4; cb++) { cx[cb][0]=0.f; cx[cb][1]=0.f; cx[cb][2]=0.f; cx[cb][3]=0.f; }
            #pragma unroll
            for (int ks = 0; ks < 2; ks++)
                #pragma unroll
                for (int cb = 0; cb < 4; cb++)
                    cx[cb] = __builtin_amdgcn_mfma_f32_16x16x32_bf16(ah[ks], w2f[cb][ks], cx[cb], 0, 0, 0);
            #pragma unroll
            for (int cb = 0; cb < 4; cb++) {
                int feat = cb * 16 + m;
                float bb = bl2[feat];
                #pragma unroll
                for (int r = 0; r < 4; r++)
                    buf[wv][(quad * 4 + r) * 136 + feat] = f2bs(fmaxf(cx[cb][r] + bb, 0.f));
            }
        }
        __builtin_amdgcn_wave_barrier();
        short8 a[4];
        a[0] = *(const short8*)&buf[wv][m * 136 + quad * 8];
        a[1] = *(const short8*)&buf[wv][m * 136 + 32 + quad * 8];
        a[2] = *(const short8*)&s[(long)(n0 + m) * 64 + quad * 8];
        a[3] = *(const short8*)&s[(long)(n0 + m) * 64 + 32 + quad * 8];
        __builtin_amdgcn_wave_barrier();
        float4v cz[4], cd[4];
        #pragma unroll
        for (int cb = 0; cb < 4; cb++) {
            cz[cb][0]=0.f; cz[cb][1]=0.f; cz[cb][2]=0.f; cz[cb][3]=0.f;
            cd[cb][0]=0.f; cd[cb][1]=0.f; cd[cb][2]=0.f; cd[cb][3]=0.f;
        }
        #pragma unroll
        for (int ks = 0; ks < 4; ks++)
            #pragma unroll
            for (int cb = 0; cb < 4; cb++)
                cz[cb] = __builtin_amdgcn_mfma_f32_16x16x32_bf16(a[ks], w1f[cb][ks], cz[cb], 0, 0, 0);
        #pragma unroll
        for (int ks = 0; ks < 2; ks++)
            #pragma unroll
            for (int cb = 0; cb < 4; cb++) {
                short8 bg = *(const short8*)&wTg[(cb * 16 + m) * 72 + ks * 32 + quad * 8];
                cd[cb] = __builtin_amdgcn_mfma_f32_16x16x32_bf16(a[2 + ks], bg, cd[cb], 0, 0, 0);
            }
        #pragma unroll
        for (int cb = 0; cb < 4; cb++) {
            int feat = cb * 16 + m;
            #pragma unroll
            for (int r = 0; r < 4; r++) {
                int row = quad * 4 + r;
                buf[wv][row * 136 + feat] = f2bs(cz[cb][r]);
                buf[wv][row * 136 + 64 + feat] = f2bs(cd[cb][r] * dinv[n0 + row]);
            }
        }
        __builtin_amdgcn_wave_barrier();
        uint4* orow = (uint4*)(zsw + (long)n0 * 128);
        #pragma unroll
        for (int it = 0; it < 4; it++) {
            int idx = it * 64 + lane;
            int row = idx >> 4, ch = idx & 15;
            orow[(long)row * 16 + ch] = *(const uint4*)&buf[wv][row * 136 + ch * 8];
        }
        __builtin_amdgcn_wave_barrier();
    }
}

// ---------------- mmC (fused pool): x'=relu(hB@W2+b2); w=[x',s]@Whp+bw; pool ----------------
__global__ __launch_bounds__(256) void k_mmC(const bf16* __restrict__ hB,
                                             const bf16* __restrict__ s,
                                             const void* __restrict__ W2,
                                             const void* __restrict__ B2,
                                             const void* __restrict__ Ww,
                                             const void* __restrict__ Bw,
                                             const int* __restrict__ batch,
                                             const int* __restrict__ flags,
                                             long w2_off, long b2_off,
                                             float* __restrict__ xp) {
    __shared__ short wT2[64 * 72];
    __shared__ short wTw[64 * 136];
    __shared__ float bl2[64], blw[64];
    __shared__ short xbuf[4][16 * 72];
    const int isf32 = flags[0];
    const int i64 = flags[1];
    const int tid = threadIdx.x;
    for (int i = tid; i < 64 * 64; i += 256) {
        int k = i >> 6, f = i & 63;
        wT2[f * 72 + k] = f2bs(ldf(W2, w2_off + i, isf32));
    }
    for (int i = tid; i < 64 * 128; i += 256) {
        int k = i >> 6, f = i & 63;
        wTw[f * 136 + k] = f2bs(ldf(Ww, i, isf32));
    }
    if (tid < 64) { bl2[tid] = ldf(B2, b2_off + tid, isf32); blw[tid] = ldf(Bw, tid, isf32); }
    __syncthreads();

    const int lane = tid & 63, wv = tid >> 6;
    const int m = lane & 15, quad = lane >> 4;

    short8 w2f[4][2], wwf[4][4];
    float bwv[4];
    #pragma unroll
    for (int cb = 0; cb < 4; cb++) {
        #pragma unroll
        for (int ks = 0; ks < 2; ks++)
            w2f[cb][ks] = *(const short8*)&wT2[(cb * 16 + m) * 72 + ks * 32 + quad * 8];
        #pragma unroll
        for (int ks = 0; ks < 4; ks++)
            wwf[cb][ks] = *(const short8*)&wTw[(cb * 16 + m) * 136 + ks * 32 + quad * 8];
        bwv[cb] = blw[cb * 16 + m];
    }

    for (int t = blockIdx.x * 4 + wv; t < NTILES; t += gridDim.x * 4) {
        const int n0 = t * 16;
        {
            short8 ah[2];
            ah[0] = *(const short8*)&hB[(long)(n0 + m) * 64 + quad * 8];
            ah[1] = *(const short8*)&hB[(long)(n0 + m) * 64 + 32 + quad * 8];
            float4v cx[4];
            #pragma unroll
            for (int cb = 0; cb < 4; cb++) { cx[cb][0]=0.f; cx[cb][1]=0.f; cx[cb][2]=0.f; cx[cb][3]=0.f; }
            #pragma unroll
            for (int ks = 0; ks < 2; ks++)
                #pragma unroll
                for (int cb = 0; cb < 4; cb++)
                    cx[cb] = __builtin_amdgcn_mfma_f32_16x16x32_bf16(ah[ks], w2f[cb][ks], cx[cb], 0, 0, 0);
            #pragma unroll
            for (int cb = 0; cb < 4; cb++) {
                int feat = cb * 16 + m;
                float bb = bl2[feat];
                #pragma unroll
                for (int r = 0; r < 4; r++)
                    xbuf[wv][(quad * 4 + r) * 72 + feat] = f2bs(fmaxf(cx[cb][r] + bb, 0.f));
            }
        }
        __builtin_amdgcn_wave_barrier();
        {
            short8 a[4];
            a[0] = *(const short8*)&xbuf[wv][m * 72 + quad * 8];
            a[1] = *(const short8*)&xbuf[wv][m * 72 + 32 + quad * 8];
            a[2] = *(const short8*)&s[(long)(n0 + m) * 64 + quad * 8];
            a[3] = *(const short8*)&s[(long)(n0 + m) * 64 + 32 + quad * 8];
            float4v cz[4];
            #pragma unroll
            for (int cb = 0; cb < 4; cb++) { cz[cb][0]=0.f; cz[cb][1]=0.f; cz[cb][2]=0.f; cz[cb][3]=0.f; }
            #pragma unroll
            for (int ks = 0; ks < 4; ks++)
                #pragma unroll
                for (int cb = 0; cb < 4; cb++)
                    cz[cb] = __builtin_amdgcn_mfma_f32_16x16x32_bf16(a[ks], wwf[cb][ks], cz[cb], 0, 0, 0);

            int myb = geti(batch, n0 + (lane & 15), i64);
            float pacc[4];
            #pragma unroll
            for (int cb = 0; cb < 4; cb++) pacc[cb] = 0.f;
            int g = __shfl(myb, quad * 4);
            #pragma unroll
            for (int r = 0; r < 4; r++) {
                int gr = __shfl(myb, quad * 4 + r);
                if (gr != g) {
                    #pragma unroll
                    for (int cb = 0; cb < 4; cb++) {
                        atomicAdd(&xp[(long)g * 64 + cb * 16 + m], pacc[cb]);
                        pacc[cb] = 0.f;
                    }
                    g = gr;
                }
                #pragma unroll
                for (int cb = 0; cb < 4; cb++)
                    pacc[cb] += cz[cb][r] + bwv[cb];
            }
            #pragma unroll
            for (int cb = 0; cb < 4; cb++)
                atomicAdd(&xp[(long)g * 64 + cb * 16 + m], pacc[cb]);
        }
        __builtin_amdgcn_wave_barrier();
    }
}

// ---------------- fused GIN+GCN gather. DV=1: per-source dinv via FMA (layer 0);
// DV=0: plain adds, zsw GCN half pre-scaled by producer (layer 1). ----------------
template <int DV>
__global__ __launch_bounds__(256) void k_gather4(const uint* __restrict__ zsw,
                                                 const int* __restrict__ row_end,
                                                 const int* __restrict__ deg,
                                                 const int* __restrict__ csr_src,
                                                 const void* __restrict__ b1,
                                                 const void* __restrict__ bg,
                                                 const float* __restrict__ dinv,
                                                 const int* __restrict__ flags,
                                                 long b_off,
                                                 uint* __restrict__ hB,
                                                 uint* __restrict__ sOut) {
    int tid = threadIdx.x;
    int wv = tid >> 6, lane = tid & 63;
    int grp = lane >> 4, sub = lane & 15;
    int n = blockIdx.x * 4 + wv;
    if (n >= N_NODES) return;
    int end = row_end[n], dg = deg[n];
    int beg = end - dg;
    int R = dg + 1;
    int myidx = n;
    if (lane > 0 && lane <= dg && lane < 64)
        myidx = __builtin_nontemporal_load(&csr_src[beg + lane - 1]);
    float mydinv = DV ? dinv[myidx] : 0.f;
    const bool ginhalf = (sub < 8);
    const uint4* zp = (const uint4*)zsw;
    float a[8];
    #pragma unroll
    for (int j = 0; j < 8; j++) a[j] = 0.f;
    int Rm = (R < 64) ? R : 64;
    {
        int r0 = grp, r1 = 4 + grp, r2 = 8 + grp, r3 = 12 + grp;
        int s0 = __shfl(myidx, r0), s1 = __shfl(myidx, r1),
            s2 = __shfl(myidx, r2), s3 = __shfl(myidx, r3);
        uint4 u0 = {0,0,0,0}, u1 = {0,0,0,0}, u2 = {0,0,0,0}, u3 = {0,0,0,0};
        if (r0 < Rm) u0 = zp[(long)s0 * 16 + sub];
        if (r1 < Rm) u1 = zp[(long)s1 * 16 + sub];
        if (r2 < Rm) u2 = zp[(long)s2 * 16 + sub];
        if (r3 < Rm) u3 = zp[(long)s3 * 16 + sub];
        if constexpr (DV) {
            float d0 = __shfl(mydinv, r0), d1 = __shfl(mydinv, r1),
                  d2 = __shfl(mydinv, r2), d3 = __shfl(mydinv, r3);
            float c0 = ginhalf ? 1.f : d0, c1 = ginhalf ? 1.f : d1,
                  c2 = ginhalf ? 1.f : d2, c3 = ginhalf ? 1.f : d3;
            a[0] = fmaf(c0, bflo(u0.x), fmaf(c1, bflo(u1.x), fmaf(c2, bflo(u2.x), fmaf(c3, bflo(u3.x), a[0]))));
            a[1] = fmaf(c0, bfhi(u0.x), fmaf(c1, bfhi(u1.x), fmaf(c2, bfhi(u2.x), fmaf(c3, bfhi(u3.x), a[1]))));
            a[2] = fmaf(c0, bflo(u0.y), fmaf(c1, bflo(u1.y), fmaf(c2, bflo(u2.y), fmaf(c3, bflo(u3.y), a[2]))));
            a[3] = fmaf(c0, bfhi(u0.y), fmaf(c1, bfhi(u1.y), fmaf(c2, bfhi(u2.y), fmaf(c3, bfhi(u3.y), a[3]))));
            a[4] = fmaf(c0, bflo(u0.z), fmaf(c1, bflo(u1.z), fmaf(c2, bflo(u2.z), fmaf(c3, bflo(u3.z), a[4]))));
            a[5] = fmaf(c0, bfhi(u0.z), fmaf(c1, bfhi(u1.z), fmaf(c2, bfhi(u2.z), fmaf(c3, bfhi(u3.z), a[5]))));
            a[6] = fmaf(c0, bflo(u0.w), fmaf(c1, bflo(u1.w), fmaf(c2, bflo(u2.w), fmaf(c3, bflo(u3.w), a[6]))));
            a[7] = fmaf(c0, bfhi(u0.w), fmaf(c1, bfhi(u1.w), fmaf(c2, bfhi(u2.w), fmaf(c3, bfhi(u3.w), a[7]))));
        } else {
            a[0] += (bflo(u0.x) + bflo(u1.x)) + (bflo(u2.x) + bflo(u3.x));
            a[1] += (bfhi(u0.x) + bfhi(u1.x)) + (bfhi(u2.x) + bfhi(u3.x));
            a[2] += (bflo(u0.y) + bflo(u1.y)) + (bflo(u2.y) + bflo(u3.y));
            a[3] += (bfhi(u0.y) + bfhi(u1.y)) + (bfhi(u2.y) + bfhi(u3.y));
            a[4] += (bflo(u0.z) + bflo(u1.z)) + (bflo(u2.z) + bflo(u3.z));
            a[5] += (bfhi(u0.z) + bfhi(u1.z)) + (bfhi(u2.z) + bfhi(u3.z));
            a[6] += (bflo(u0.w) + bflo(u1.w)) + (bflo(u2.w) + bflo(u3.w));
            a[7] += (bfhi(u0.w) + bfhi(u1.w)) + (bfhi(u2.w) + bfhi(u3.w));
        }
    }
    for (int i = 16; i < Rm; i += 4) {
        int r = i + grp;
        int sr = __shfl(myidx, r);
        uint4 u = {0,0,0,0};
        if (r < Rm) u = zp[(long)sr * 16 + sub];
        if constexpr (DV) {
            float dr = __shfl(mydinv, r);
            float cc = ginhalf ? 1.f : dr;
            a[0] = fmaf(cc, bflo(u.x), a[0]); a[1] = fmaf(cc, bfhi(u.x), a[1]);
            a[2] = fmaf(cc, bflo(u.y), a[2]); a[3] = fmaf(cc, bfhi(u.y), a[3]);
            a[4] = fmaf(cc, bflo(u.z), a[4]); a[5] = fmaf(cc, bfhi(u.z), a[5]);
            a[6] = fmaf(cc, bflo(u.w), a[6]); a[7] = fmaf(cc, bfhi(u.w), a[7]);
        } else {
            a[0] += bflo(u.x); a[1] += bfhi(u.x);
            a[2] += bflo(u.y); a[3] += bfhi(u.y);
            a[4] += bflo(u.z); a[5] += bfhi(u.z);
            a[6] += bflo(u.w); a[7] += bfhi(u.w);
        }
    }
    // rare tail for deg > 63 (correctness only)
    for (int i = 64; i < R; i += 8) {
        int iA = i + grp, iB = i + 4 + grp;
        uint4 uA = {0,0,0,0}, uB = {0,0,0,0};
        float cA = 1.f, cB = 1.f;
        if (iA < R) {
            int sA = __builtin_nontemporal_load(&csr_src[beg + iA - 1]);
            uA = zp[(long)sA * 16 + sub];
            if (DV && !ginhalf) cA = dinv[sA];
        }
        if (iB < R) {
            int sB = __builtin_nontemporal_load(&csr_src[beg + iB - 1]);
            uB = zp[(long)sB * 16 + sub];
            if (DV && !ginhalf) cB = dinv[sB];
        }
        a[0] = fmaf(cA, bflo(uA.x), fmaf(cB, bflo(uB.x), a[0]));
        a[1] = fmaf(cA, bfhi(uA.x), fmaf(cB, bfhi(uB.x), a[1]));
        a[2] = fmaf(cA, bflo(uA.y), fmaf(cB, bflo(uB.y), a[2]));
        a[3] = fmaf(cA, bfhi(uA.y), fmaf(cB, bfhi(uB.y), a[3]));
        a[4] = fmaf(cA, bflo(uA.z), fmaf(cB, bflo(uB.z), a[4]));
        a[5] = fmaf(cA, bfhi(uA.z), fmaf(cB, bfhi(uB.z), a[5]));
        a[6] = fmaf(cA, bflo(uA.w), fmaf(cB, bflo(uB.w), a[6]));
        a[7] = fmaf(cA, bfhi(uA.w), fmaf(cB, bfhi(uB.w), a[7]));
    }
    #pragma unroll
    for (int j = 0; j < 8; j++) {
        a[j] += __shfl_xor(a[j], 16);
        a[j] += __shfl_xor(a[j], 32);
    }
    int q = 4 * sub + grp;
    float v0 = a[2 * grp], v1 = a[2 * grp + 1];
    int isf32 = flags[0];
    if (q < 32) {
        float c0 = ldf(b1, b_off + 2 * q, isf32);
        float c1 = ldf(b1, b_off + 2 * q + 1, isf32);
        hB[(long)n * 32 + q] = packbf(fmaxf(v0 + c0, 0.f), fmaxf(v1 + c1, 0.f));
    } else {
        int qq = q - 32;
        float c0 = ldf(bg, b_off + 2 * qq, isf32);
        float c1 = ldf(bg, b_off + 2 * qq + 1, isf32);
        float dn = dinv[n];
        sOut[(long)n * 32 + qq] = packbf(tanhfast(dn * v0 + c0), tanhfast(dn * v1 + c1));
    }
}

// ---------------- final: post + readout + log_softmax ----------------
__global__ __launch_bounds__(64) void k_final(const float* __restrict__ xp,
                                              const void* __restrict__ post_w,
                                              const void* __restrict__ post_b,
                                              const void* __restrict__ ro_w,
                                              const void* __restrict__ ro_b,
                                              const int* __restrict__ flags,
                                              void* __restrict__ out) {
    __shared__ float h2[64];
    __shared__ float lg[16];
    int isf32 = flags[0];
    int g = blockIdx.x;
    int f = threadIdx.x;
    float xr = xp[(long)g * 64 + f];
    float acc = ldf(post_b, f, isf32);
    #pragma unroll
    for (int j = 0; j < 64; j++) acc += __shfl(xr, j) * ldf(post_w, j * 64 + f, isf32);
    float v = fmaxf(acc, 0.f);
    h2[f] = v;
    long oxp = (long)g * 64 + f;
    if (isf32) ((float*)out)[oxp] = v; else ((bf16*)out)[oxp] = f2b(v);
    __syncthreads();
    if (f < 16) {
        float a = ldf(ro_b, f, isf32);
        for (int j = 0; j < 64; j++) a += h2[j] * ldf(ro_w, j * 16 + f, isf32);
        lg[f] = a;
    }
    __syncthreads();
    if (f < 16) {
        float m = -1e30f;
        for (int j = 0; j < 16; j++) m = fmaxf(m, lg[j]);
        float sum = 0.f;
        for (int j = 0; j < 16; j++) sum += expf(lg[j] - m);
        long oy = (long)N_GRAPHS * 64 + (long)g * 16 + f;
        float yv = lg[f] - m - logf(sum);
        if (isf32) ((float*)out)[oy] = yv; else ((bf16*)out)[oy] = f2b(yv);
    }
}

extern "C" void kernel_launch(void* const* d_in, const int* in_sizes, int n_in,
                              void* d_out, int out_size, void* d_ws, size_t ws_size,
                              hipStream_t stream) {
    const void* x_in  = d_in[0];
    const void* s_in  = d_in[1];
    const int*  ei    = (const int*)d_in[2];
    const int*  batch = (const int*)d_in[3];
    const void* pre_w = d_in[4];
    const void* pre_b = d_in[5];
    const void* emb_w = d_in[6];
    const void* emb_b = d_in[7];
    const void* gin_w1 = d_in[8];
    const void* gin_b1 = d_in[9];
    const void* gin_w2 = d_in[10];
    const void* gin_b2 = d_in[11];
    const void* gcn_w  = d_in[12];
    const void* gcn_b  = d_in[13];
    const void* whp_w  = d_in[14];
    const void* whp_b  = d_in[15];
    const void* post_w = d_in[16];
    const void* post_b = d_in[17];
    const void* ro_w   = d_in[18];
    const void* ro_b   = d_in[19];

    int* flags   = (int*)d_ws;
    int* deg     = flags + 64;
    int* row_end = deg + N_NODES;
    int* hist    = row_end + N_NODES;          // [NBUCK][256]
    int* lsc     = hist + 256 * NBUCK;         // [NBUCK][256]
    uint* bstore = (uint*)(lsc + 256 * NBUCK); // [256][BST]
    int* csr_src = (int*)(bstore + (long)256 * BST);
    float* dinv  = (float*)(csr_src + N_EDGES);
    bf16* x0     = (bf16*)(dinv + N_NODES);
    bf16* sA     = x0 + (long)N_NODES * 64;
    bf16* hB     = sA + (long)N_NODES * 64;
    uint* zsw    = (uint*)(hB + (long)N_NODES * 64);
    float* xp    = (float*)(zsw + (long)N_NODES * 64);

    const int GGB = (N_NODES + 3) / 4;       // 25000

    // front: detect + CSR partition + pre/emb GEMM + xp zero, one overlapped dispatch
    k_front<<<897, 256, 0, stream>>>(ei, x_in, pre_w, pre_b, s_in, emb_w, emb_b,
                                     bstore, hist, lsc, flags, x0, sA, xp);

    const long W1 = 128 * 64, W2 = 64 * 64, WG = 64 * 64, B = 64;

    // ---- CSR finalize + layer-0 GEMM merged (k4 blocks first) ----
    k4_mmA<<<NBUCK + 768, 256, 0, stream>>>(bstore, hist, lsc, deg, dinv, row_end, csr_src,
                                            x0, sA, gin_w1, gcn_w, flags, (bf16*)zsw);
    k_gather4<1><<<GGB, 256, 0, stream>>>(zsw, row_end, deg, csr_src, gin_b1, gcn_b, dinv, flags, 0L, (uint*)hB, (uint*)sA);

    // ---- layer 0 tail fused with layer 1 head (GCN half pre-scaled by dinv) ----
    k_mmB<<<512, 256, 0, stream>>>(hB, sA, gin_w2, gin_b2, gin_w1, gcn_w, dinv, flags,
                                   0L, 0L, W1, WG, (bf16*)zsw);
    k_gather4<0><<<GGB, 256, 0, stream>>>(zsw, row_end, deg, csr_src, gin_b1, gcn_b, dinv, flags, B, (uint*)hB, (uint*)sA);

    // ---- layer 1 tail + whp + pool fused; final ----
    k_mmC<<<512, 256, 0, stream>>>(hB, sA, gin_w2, gin_b2, whp_w, whp_b, batch, flags, W2, B, xp);

    k_final<<<N_GRAPHS, 64, 0, stream>>>(xp, post_w, post_b, ro_w, ro_b, flags, d_out);
}